// Round 1
// baseline (90.951 us; speedup 1.0000x reference)
//
#include <hip/hip_runtime.h>

typedef float v2f __attribute__((ext_vector_type(2)));

#define N_ROWS 131072
#define DIM    256
#define KP     16
#define NDOM   8
#define NB     32      // bins
#define GG     100     // barycenter grid

#define EB_SZ   (NDOM*KP*(NB+1))   // 4224
#define BARY_SZ (KP*GG)            // 1600

#define GRID   512
#define WAVES  4
#define NWAVE  (GRID*WAVES)        // 2048 waves
#define ITERS  (N_ROWS/NWAVE)      // 64 rows per wave, exact

__device__ __forceinline__ void pk_fma(v2f &d, v2f a, v2f b) {
    // d = a*b + d (packed 2x f32). Required to be memory-bound (plain FMA is 56us > 43us floor).
    asm("v_pk_fma_f32 %0, %1, %2, %0" : "+v"(d) : "v"(a), "v"(b));
}

__device__ __forceinline__ void wave_fence() {
    // wave-local LDS visibility: lockstep lanes + drained LDS queue.
    asm volatile("s_waitcnt lgkmcnt(0)" ::: "memory");
    __builtin_amdgcn_sched_barrier(0);  // rule #18: pin following ops behind the wait
}

__global__ __launch_bounds__(256, 2)
void inb_kernel(const float* __restrict__ X, const int* __restrict__ y,
                const float* __restrict__ wT, const float* __restrict__ be,
                const float* __restrict__ cv, const float* __restrict__ bq,
                float* __restrict__ out)
{
    __shared__ alignas(16) float sEB[EB_SZ];
    __shared__ alignas(16) float sCDF[EB_SZ];
    __shared__ alignas(16) float sBARY[BARY_SZ];
    __shared__ alignas(16) float sROW[WAVES][272];   // 256 + 4-per-64 g-pad
    __shared__ alignas(16) float sCOEFF[WAVES][16];

    const int tid = threadIdx.x;
    // cooperative table staging (amortized over 256 rows/block)
    for (int i = tid; i < EB_SZ; i += 256) { sEB[i] = be[i]; sCDF[i] = cv[i]; }
    for (int i = tid; i < BARY_SZ; i += 256) sBARY[i] = bq[i];
    __syncthreads();

    const int lane = tid & 63;
    const int wid  = tid >> 6;
    const int k    = lane & 15;   // projection index this lane owns
    const int g    = lane >> 4;   // 64-dim group this lane dots

    // ---- wT register slices (loop-invariant, ~128 VGPR) ----
    // projection slice: column k, dims [64g, 64g+64)
    v2f wTp[32];
#pragma unroll
    for (int t2 = 0; t2 < 32; ++t2) {
        int d0 = 64*g + 2*t2;
        v2f w; w[0] = wT[d0*KP + k]; w[1] = wT[(d0+1)*KP + k];
        wTp[t2] = w;
    }
    // output slice: rows 4*lane..4*lane+3, all 16 k (contiguous pairs)
    v2f wTo[4][8];
#pragma unroll
    for (int j = 0; j < 4; ++j) {
        const float4* wrow = reinterpret_cast<const float4*>(&wT[(4*lane + j)*KP]);
#pragma unroll
        for (int q = 0; q < 4; ++q) {
            float4 v = wrow[q];
            v2f a; a[0] = v.x; a[1] = v.y; wTo[j][2*q]   = a;
            v2f b; b[0] = v.z; b[1] = v.w; wTo[j][2*q+1] = b;
        }
    }

    float* rowbuf = sROW[wid];
    float* cobuf  = sCOEFF[wid];
    const int gwave = blockIdx.x * WAVES + wid;
    const int widx  = 4*lane + 4*g;          // padded LDS write index

    // prefetch distance 2 (cover ~900cy HBM latency)
    float4 xa = *reinterpret_cast<const float4*>(&X[(size_t)gwave*DIM + 4*lane]);
    float4 xb = *reinterpret_cast<const float4*>(&X[(size_t)(gwave + NWAVE)*DIM + 4*lane]);

    for (int it = 0; it < ITERS; ++it) {
        const int row = gwave + it*NWAVE;

        // stage current row to LDS (padded: conflict-free proj reads)
        *reinterpret_cast<float4*>(&rowbuf[widx]) = xa;

        // prefetch row+2
        float4 xc = {0.f,0.f,0.f,0.f};
        if (it + 2 < ITERS)
            xc = *reinterpret_cast<const float4*>(&X[(size_t)(row + 2*NWAVE)*DIM + 4*lane]);

        const int dom = y[row];

        wave_fence();

        // ---- projection: p = dot(X[row][64g..64g+63], wT[.,k]) ----
        v2f acc0 = {0.f,0.f}, acc1 = {0.f,0.f};
#pragma unroll
        for (int t = 0; t < 16; ++t) {
            float4 xv = *reinterpret_cast<const float4*>(&rowbuf[68*g + 4*t]);
            v2f lo; lo[0] = xv.x; lo[1] = xv.y;
            v2f hi; hi[0] = xv.z; hi[1] = xv.w;
            pk_fma(acc0, lo, wTp[2*t]);
            pk_fma(acc1, hi, wTp[2*t+1]);
        }
        float p = acc0[0] + acc0[1] + acc1[0] + acc1[1];
        p += __shfl_xor(p, 16);
        p += __shfl_xor(p, 32);   // all lanes now hold Xm[row][k]
        const float xm = p;

        // ---- per-k scalar phase (g-redundant, no divergence) ----
        const float* eb = &sEB [(dom*KP + k)*(NB+1)];
        const float* cf = &sCDF[(dom*KP + k)*(NB+1)];
        // branchless binary search: lo = largest idx with eb[idx] <= xm (ss-1), in [-1,32]
        int blo = -1, bhi = NB + 1;
#pragma unroll
        for (int itr = 0; itr < 6; ++itr) {
            int mid = (blo + bhi) >> 1;
            float e = eb[mid];
            bool le = (e <= xm);
            blo = le ? mid : blo;
            bhi = le ? bhi : mid;
        }
        int i0 = min(max(blo, 0), NB - 1);
        float x0 = eb[i0], x1 = eb[i0+1];
        float f0 = cf[i0], f1 = cf[i0+1];
        float t  = fminf(fmaxf(__fdividef(xm - x0, x1 - x0), 0.f), 1.f);
        float u  = f0 + t * (f1 - f0);
        float posv = fminf(fmaxf(u, 0.f), 1.f) * (float)(GG - 1);
        int jj = min((int)posv, GG - 2);
        float ttf = posv - (float)jj;
        const float* bqk = &sBARY[k*GG];
        float b0 = bqk[jj], b1 = bqk[jj+1];
        float z = b0*(1.f - ttf) + b1*ttf;
        float coeff = xm - z;                 // out = X - coeff @ wT.T

        if (g == 0) cobuf[k] = coeff;
        wave_fence();

        // ---- output: out[d] = x[d] - sum_k coeff[k]*wT[d][k], d = 4*lane+j ----
        v2f c2[8];
#pragma unroll
        for (int q = 0; q < 4; ++q) {
            float4 cv4 = *reinterpret_cast<const float4*>(&cobuf[4*q]);
            v2f a; a[0] = cv4.x; a[1] = cv4.y; c2[2*q]   = a;
            v2f b; b[0] = cv4.z; b[1] = cv4.w; c2[2*q+1] = b;
        }
        const float xr[4] = {xa.x, xa.y, xa.z, xa.w};
        float od[4];
#pragma unroll
        for (int j = 0; j < 4; ++j) {
            v2f a = {0.f,0.f};
#pragma unroll
            for (int q = 0; q < 8; ++q) pk_fma(a, c2[q], wTo[j][q]);
            od[j] = xr[j] - (a[0] + a[1]);
        }
        float4 o4; o4.x = od[0]; o4.y = od[1]; o4.z = od[2]; o4.w = od[3];
        *reinterpret_cast<float4*>(&out[(size_t)row*DIM + 4*lane]) = o4;

        xa = xb; xb = xc;
    }
}

extern "C" void kernel_launch(void* const* d_in, const int* in_sizes, int n_in,
                              void* d_out, int out_size, void* d_ws, size_t ws_size,
                              hipStream_t stream) {
    const float* X  = (const float*)d_in[0];
    const int*   y  = (const int*)  d_in[1];
    const float* wT = (const float*)d_in[2];
    const float* be = (const float*)d_in[3];
    const float* cv = (const float*)d_in[4];
    const float* bq = (const float*)d_in[5];
    float* out = (float*)d_out;
    hipLaunchKernelGGL(inb_kernel, dim3(GRID), dim3(256), 0, stream,
                       X, y, wT, be, cv, bq, out);
}